// Round 2
// baseline (420.521 us; speedup 1.0000x reference)
//
#include <hip/hip_runtime.h>
#include <stdint.h>

// B=4, T=2048, C=1024, H=16, D=64.
// Inputs/outputs are FP32 (per reference). Internal compute: bf16 MFMA, fp32 accum.

using u16 = unsigned short;
typedef __attribute__((ext_vector_type(8))) __bf16 bf16x8;
typedef __attribute__((ext_vector_type(4))) float  floatx4;

#define LOG2E 1.44269504088896340736f

__device__ __forceinline__ u16 f2b(float f) {
    union { float f; unsigned int i; } x; x.f = f;
    unsigned int r = (x.i + 0x7fffu + ((x.i >> 16) & 1u)) >> 16;
    return (u16)r;
}
__device__ __forceinline__ bf16x8 ld16B(const u16* p) {
    bf16x8 v; __builtin_memcpy(&v, p, 16); return v;
}
// async global->LDS, 16B/lane; lds ptr must be wave-uniform (HW writes base + lane*16)
__device__ __forceinline__ void async16(const u16* g, u16* l) {
    __builtin_amdgcn_global_load_lds((const __attribute__((address_space(1))) unsigned int*)g,
                                     (__attribute__((address_space(3))) unsigned int*)l,
                                     16, 0, 0);
}

__device__ __forceinline__ void store_out(u16* p, float v)   { *p = f2b(v); }
__device__ __forceinline__ void store_out(float* p, float v) { *p = v; }

// ---------------- convert fp32 -> bf16 (x + 4 weight matrices) ----------------
// x: 8M elems, each W: 1M elems. total 12M. 4 elems/thread.
__global__ __launch_bounds__(256) void convert_kernel(
    const float* __restrict__ x,
    const float* __restrict__ Wq, const float* __restrict__ Wk,
    const float* __restrict__ Wv, const float* __restrict__ Wo,
    u16* __restrict__ xb, u16* __restrict__ wqb, u16* __restrict__ wkb,
    u16* __restrict__ wvb, u16* __restrict__ wob)
{
    size_t e = ((size_t)blockIdx.x * 256 + threadIdx.x) * 4;
    const float* src; u16* dst; size_t off;
    const size_t XN = (size_t)8 << 20;
    if (e < XN) { src = x; dst = xb; off = e; }
    else {
        size_t k = e - XN;
        int w = (int)(k >> 20);
        off = k & ((1u << 20) - 1);
        src = (w == 0) ? Wq : (w == 1) ? Wk : (w == 2) ? Wv : Wo;
        dst = (w == 0) ? wqb : (w == 1) ? wkb : (w == 2) ? wvb : wob;
    }
    float4 f = *(const float4*)(src + off);
    u16 o[4] = { f2b(f.x), f2b(f.y), f2b(f.z), f2b(f.w) };
    __builtin_memcpy(dst + off, o, 8);
}

// ---------------- GEMM: C[m,n] = A[m,:] . W[n,:] + bias[n]  (bt form) ----------------
// M=8192, N=1024, K=1024 (bf16 A and W). 128x128 tile, BK=64, 4 waves each 64x64.
// LDS swizzle: row r, logical granule kg (8 bf16) stored at physical granule kg^(r&7).
template <int BHTD, typename OutT>
__device__ __forceinline__ void gemm_bt_body(const u16* __restrict__ A,
                                             const u16* __restrict__ W,
                                             const float* __restrict__ bias,
                                             OutT* __restrict__ out,
                                             int m0, int n0)
{
    constexpr int K = 1024;
    __shared__ __align__(16) u16 sA[128 * 64];
    __shared__ __align__(16) u16 sB[128 * 64];

    const int tid  = threadIdx.x;
    const int wave = tid >> 6, lane = tid & 63;
    const int wr = wave >> 1, wc = wave & 1;
    const int quad = lane >> 4, l15 = lane & 15;

    floatx4 acc[4][4];
    #pragma unroll
    for (int i = 0; i < 4; ++i)
        #pragma unroll
        for (int j = 0; j < 4; ++j)
            acc[i][j] = (floatx4){0.f, 0.f, 0.f, 0.f};

    #pragma unroll 1
    for (int kb = 0; kb < 16; ++kb) {
        __syncthreads();                       // everyone done reading previous tile
        const int k0 = kb * 64;
        #pragma unroll
        for (int j = 0; j < 4; ++j) {          // wave stages 32 rows of A and of B
            int r  = wave * 32 + j * 8 + (lane >> 3);
            int kg = (lane & 7) ^ (r & 7);
            async16(A + (size_t)(m0 + r) * K + k0 + kg * 8, &sA[(wave * 32 + j * 8) * 64]);
            async16(W + (size_t)(n0 + r) * K + k0 + kg * 8, &sB[(wave * 32 + j * 8) * 64]);
        }
        __syncthreads();                       // drains vmcnt (global_load_lds) too

        #pragma unroll
        for (int kk = 0; kk < 2; ++kk) {
            bf16x8 af[4], bf[4];
            const int kg = kk * 4 + quad;
            #pragma unroll
            for (int t = 0; t < 4; ++t) {
                int ra = wr * 64 + t * 16 + l15;
                af[t] = ld16B(&sA[ra * 64 + ((kg ^ (ra & 7)) * 8)]);
                int rb = wc * 64 + t * 16 + l15;
                bf[t] = ld16B(&sB[rb * 64 + ((kg ^ (rb & 7)) * 8)]);
            }
            #pragma unroll
            for (int mt = 0; mt < 4; ++mt)
                #pragma unroll
                for (int nt = 0; nt < 4; ++nt)
                    acc[mt][nt] = __builtin_amdgcn_mfma_f32_16x16x32_bf16(af[mt], bf[nt], acc[mt][nt], 0, 0, 0);
        }
    }

    // epilogue: C-layout col=lane&15, row=quad*4+r
    #pragma unroll
    for (int nt = 0; nt < 4; ++nt) {
        int col  = n0 + wc * 64 + nt * 16 + l15;
        float bv = bias[col];
        #pragma unroll
        for (int mt = 0; mt < 4; ++mt) {
            #pragma unroll
            for (int r = 0; r < 4; ++r) {
                int row = m0 + wr * 64 + mt * 16 + quad * 4 + r;
                float v = acc[mt][nt][r] + bv;
                int idx;
                if (BHTD) {  // out[b][h][t][d], b=row>>11, t=row&2047, h=col>>6, d=col&63
                    idx = (((row >> 11) * 16 + (col >> 6)) * 2048 + (row & 2047)) * 64 + (col & 63);
                } else {     // row-major [M, 1024]
                    idx = row * 1024 + col;
                }
                store_out(&out[idx], v);
            }
        }
    }
}

__global__ __launch_bounds__(256) void qkv_kernel(
    const u16* __restrict__ x,
    const u16* __restrict__ Wq, const u16* __restrict__ Wk, const u16* __restrict__ Wv,
    const float* __restrict__ bq, const float* __restrict__ bk, const float* __restrict__ bv,
    u16* __restrict__ q, u16* __restrict__ k, u16* __restrict__ v)
{
    const int z = blockIdx.z;
    const u16*   W  = (z == 0) ? Wq : (z == 1) ? Wk : Wv;
    const float* bb = (z == 0) ? bq : (z == 1) ? bk : bv;
    u16*         o  = (z == 0) ? q  : (z == 1) ? k  : v;
    gemm_bt_body<1, u16>(x, W, bb, o, blockIdx.y * 128, blockIdx.x * 128);
}

__global__ __launch_bounds__(256) void proj_kernel(
    const u16* __restrict__ y, const u16* __restrict__ Wo, const float* __restrict__ bo,
    float* __restrict__ out)
{
    gemm_bt_body<0, float>(y, Wo, bo, out, blockIdx.y * 128, blockIdx.x * 128);
}

// ---------------- Flash attention ----------------
// grid (T/64=32, B*H=64), block 256 (4 waves). Wave w owns Q rows [64*qt+16w, +16).
__global__ __launch_bounds__(256) void attn_kernel(
    const u16* __restrict__ Q, const u16* __restrict__ K,
    const u16* __restrict__ V, u16* __restrict__ Y)
{
    const int qt = blockIdx.x, bh = blockIdx.y;
    const int tid = threadIdx.x;
    const int wave = tid >> 6, lane = tid & 63;
    const int quad = lane >> 4, l15 = lane & 15;

    __shared__ __align__(16) u16 sK[64 * 64];      // swizzled, like GEMM tiles
    __shared__ __align__(16) u16 sVt[64 * 72];     // Vt[d][tk], row stride 72 (16B-aligned rows)
    __shared__ __align__(16) u16 sP[4][16 * 72];   // per-wave P tile, row stride 72

    const size_t base = (size_t)bh * (2048 * 64);

    // Q A-fragments in registers for the whole kernel
    bf16x8 qf[2];
    {
        int row = qt * 64 + wave * 16 + l15;
        const u16* qp = Q + base + (size_t)row * 64 + quad * 8;
        qf[0] = ld16B(qp);
        qf[1] = ld16B(qp + 32);
    }

    floatx4 accO[4];
    #pragma unroll
    for (int nt = 0; nt < 4; ++nt) accO[nt] = (floatx4){0.f, 0.f, 0.f, 0.f};
    float m_r[4], l_r[4];
    #pragma unroll
    for (int r = 0; r < 4; ++r) { m_r[r] = -1e30f; l_r[r] = 0.f; }

    #pragma unroll 1
    for (int kt = 0; kt < 32; ++kt) {
        __syncthreads();
        // stage K tile (swizzled) via async DMA
        #pragma unroll
        for (int j = 0; j < 2; ++j) {
            int r  = wave * 16 + j * 8 + (lane >> 3);
            int kg = (lane & 7) ^ (r & 7);
            async16(K + base + (size_t)(kt * 64 + r) * 64 + kg * 8, &sK[(wave * 16 + j * 8) * 64]);
        }
        // stage V transposed: coalesced row reads, vector LDS write
        {
            int d = tid & 63;
            #pragma unroll
            for (int gg = 0; gg < 2; ++gg) {
                int tkg = (tid >> 6) + gg * 4;
                u16 tmp[8];
                #pragma unroll
                for (int jj = 0; jj < 8; ++jj)
                    tmp[jj] = V[base + (size_t)(kt * 64 + tkg * 8 + jj) * 64 + d];
                __builtin_memcpy(&sVt[d * 72 + tkg * 8], tmp, 16);
            }
        }
        __syncthreads();

        // S = Q K^T  (16 x 64 per wave)
        floatx4 s[4];
        #pragma unroll
        for (int nt = 0; nt < 4; ++nt) s[nt] = (floatx4){0.f, 0.f, 0.f, 0.f};
        #pragma unroll
        for (int kk = 0; kk < 2; ++kk) {
            const int kg = kk * 4 + quad;
            #pragma unroll
            for (int nt = 0; nt < 4; ++nt) {
                int rb = nt * 16 + l15;
                bf16x8 kf = ld16B(&sK[rb * 64 + ((kg ^ (rb & 7)) * 8)]);
                s[nt] = __builtin_amdgcn_mfma_f32_16x16x32_bf16(qf[kk], kf, s[nt], 0, 0, 0);
            }
        }
        #pragma unroll
        for (int nt = 0; nt < 4; ++nt)
            #pragma unroll
            for (int r = 0; r < 4; ++r) s[nt][r] *= 0.125f;   // 1/sqrt(64)

        // online softmax; row stats across nt (in-lane) and the 16-lane col group
        float alpha[4];
        #pragma unroll
        for (int r = 0; r < 4; ++r) {
            float mx = fmaxf(fmaxf(s[0][r], s[1][r]), fmaxf(s[2][r], s[3][r]));
            mx = fmaxf(mx, __shfl_xor(mx, 1));
            mx = fmaxf(mx, __shfl_xor(mx, 2));
            mx = fmaxf(mx, __shfl_xor(mx, 4));
            mx = fmaxf(mx, __shfl_xor(mx, 8));
            float mn = fmaxf(m_r[r], mx);
            alpha[r] = __builtin_amdgcn_exp2f((m_r[r] - mn) * LOG2E);
            m_r[r] = mn;
        }
        float rs[4] = {0.f, 0.f, 0.f, 0.f};
        u16 pb[4][4];
        #pragma unroll
        for (int nt = 0; nt < 4; ++nt)
            #pragma unroll
            for (int r = 0; r < 4; ++r) {
                float p = __builtin_amdgcn_exp2f((s[nt][r] - m_r[r]) * LOG2E);
                rs[r] += p;
                pb[nt][r] = f2b(p);
            }
        #pragma unroll
        for (int r = 0; r < 4; ++r) {
            rs[r] += __shfl_xor(rs[r], 1);
            rs[r] += __shfl_xor(rs[r], 2);
            rs[r] += __shfl_xor(rs[r], 4);
            rs[r] += __shfl_xor(rs[r], 8);
            l_r[r] = l_r[r] * alpha[r] + rs[r];
        }

        // P: C-layout -> A-layout via wave-private LDS round-trip
        u16* sp = sP[wave];
        #pragma unroll
        for (int nt = 0; nt < 4; ++nt)
            #pragma unroll
            for (int r = 0; r < 4; ++r)
                sp[(quad * 4 + r) * 72 + nt * 16 + l15] = pb[nt][r];

        // O = O*alpha + P.V
        #pragma unroll
        for (int nt = 0; nt < 4; ++nt)
            #pragma unroll
            for (int r = 0; r < 4; ++r) accO[nt][r] *= alpha[r];
        #pragma unroll
        for (int kk = 0; kk < 2; ++kk) {
            bf16x8 pf = ld16B(&sp[l15 * 72 + kk * 32 + quad * 8]);
            #pragma unroll
            for (int nt = 0; nt < 4; ++nt) {
                bf16x8 vf = ld16B(&sVt[(nt * 16 + l15) * 72 + kk * 32 + quad * 8]);
                accO[nt] = __builtin_amdgcn_mfma_f32_16x16x32_bf16(pf, vf, accO[nt], 0, 0, 0);
            }
        }
    }

    // epilogue: Y[b][t][h*64+d]  (Y is the [B,T,C] bf16 input of the output projection)
    const int b = bh >> 4, h = bh & 15;
    #pragma unroll
    for (int r = 0; r < 4; ++r) {
        float inv = 1.f / l_r[r];
        int t = qt * 64 + wave * 16 + quad * 4 + r;
        size_t rowbase = ((size_t)(b * 2048 + t)) * 1024 + h * 64;
        #pragma unroll
        for (int nt = 0; nt < 4; ++nt)
            Y[rowbase + nt * 16 + l15] = f2b(accO[nt][r] * inv);
    }
}

// ---------------- launch ----------------
extern "C" void kernel_launch(void* const* d_in, const int* in_sizes, int n_in,
                              void* d_out, int out_size, void* d_ws, size_t ws_size,
                              hipStream_t stream)
{
    const float* x  = (const float*)d_in[0];
    const float* Wq = (const float*)d_in[1];
    const float* bq = (const float*)d_in[2];
    const float* Wk = (const float*)d_in[3];
    const float* bk = (const float*)d_in[4];
    const float* Wv = (const float*)d_in[5];
    const float* bv = (const float*)d_in[6];
    const float* Wo = (const float*)d_in[7];
    const float* bo = (const float*)d_in[8];
    float* out = (float*)d_out;

    const size_t NTOK = (size_t)8192 * 1024;   // B*T*C elements
    const size_t WN   = (size_t)1024 * 1024;
    u16* xb  = (u16*)d_ws;            // 8M
    u16* wqb = xb + NTOK;             // 1M each
    u16* wkb = wqb + WN;
    u16* wvb = wkb + WN;
    u16* wob = wvb + WN;
    u16* q   = wob + WN;              // 8M each
    u16* k   = q + NTOK;
    u16* v   = k + NTOK;
    u16* y   = v + NTOK;

    convert_kernel<<<dim3(12288), 256, 0, stream>>>(x, Wq, Wk, Wv, Wo, xb, wqb, wkb, wvb, wob);
    qkv_kernel<<<dim3(8, 64, 3), 256, 0, stream>>>(xb, wqb, wkb, wvb, bq, bk, bv, q, k, v);
    attn_kernel<<<dim3(32, 64), 256, 0, stream>>>(q, k, v, y);
    proj_kernel<<<dim3(8, 64), 256, 0, stream>>>(y, wob, bo, out);
}

// Round 3
// 321.482 us; speedup vs baseline: 1.3081x; 1.3081x over previous
//
#include <hip/hip_runtime.h>
#include <stdint.h>

// B=4, T=2048, C=1024, H=16, D=64.
// Inputs/outputs FP32 (per reference). Internal: bf16 MFMA, fp32 accum.

using u16 = unsigned short;
using u32 = unsigned int;
typedef __attribute__((ext_vector_type(8))) __bf16 bf16x8;
typedef __attribute__((ext_vector_type(4))) float  floatx4;

#define QSCALE 0.18033688011112043f   // 0.125 * log2(e), folded into Q projection

__device__ __forceinline__ u16 f2b(float f) {
    union { float f; u32 i; } x; x.f = f;
    return (u16)((x.i + 0x7fffu + ((x.i >> 16) & 1u)) >> 16);
}
__device__ __forceinline__ u32 fbits(float f) { union { float f; u32 i; } x; x.f = f; return x.i; }
// pack two fp32 -> (bf16(b)<<16)|bf16(a) : 2 adds + 1 v_perm
__device__ __forceinline__ u32 pkbf(float a, float b) {
    u32 ia = fbits(a) + 0x8000u, ib = fbits(b) + 0x8000u;
    return __builtin_amdgcn_perm(ib, ia, 0x07060302u);
}
__device__ __forceinline__ bf16x8 ld16B(const u16* p) {
    bf16x8 v; __builtin_memcpy(&v, p, 16); return v;
}
__device__ __forceinline__ void async16(const u16* g, u16* l) {
    __builtin_amdgcn_global_load_lds((const __attribute__((address_space(1))) unsigned int*)g,
                                     (__attribute__((address_space(3))) unsigned int*)l,
                                     16, 0, 0);
}

// ---------------- convert fp32 -> bf16 (x + 4 weight matrices) ----------------
__global__ __launch_bounds__(256) void convert_kernel(
    const float* __restrict__ x,
    const float* __restrict__ Wq, const float* __restrict__ Wk,
    const float* __restrict__ Wv, const float* __restrict__ Wo,
    u16* __restrict__ xb, u16* __restrict__ wqb, u16* __restrict__ wkb,
    u16* __restrict__ wvb, u16* __restrict__ wob)
{
    size_t e = ((size_t)blockIdx.x * 256 + threadIdx.x) * 4;
    const float* src; u16* dst; size_t off;
    const size_t XN = (size_t)8 << 20;
    if (e < XN) { src = x; dst = xb; off = e; }
    else {
        size_t k = e - XN;
        int w = (int)(k >> 20);
        off = k & ((1u << 20) - 1);
        src = (w == 0) ? Wq : (w == 1) ? Wk : (w == 2) ? Wv : Wo;
        dst = (w == 0) ? wqb : (w == 1) ? wkb : (w == 2) ? wvb : wob;
    }
    float4 f = *(const float4*)(src + off);
    u32 dws[2] = { pkbf(f.x, f.y), pkbf(f.z, f.w) };
    __builtin_memcpy(dst + off, dws, 8);
}

// ---------------- GEMM: C[m,n] = A[m,:].W[n,:] + bias[n] ----------------
// MODE 0: u16 out, [b][h][t][d] layout, value scaled by `scale` (Q/K)
// MODE 1: u16 out, V^T layout [b][h][d][t], packed b64 stores
// MODE 2: f32 out, row-major [M,1024] (final projection)
template <int MODE, typename OutT>
__device__ __forceinline__ void gemm_bt_body(const u16* __restrict__ A,
                                             const u16* __restrict__ W,
                                             const float* __restrict__ bias,
                                             OutT* __restrict__ out,
                                             int m0, int n0, float scale)
{
    constexpr int K = 1024;
    __shared__ __align__(16) u16 sA[128 * 64];
    __shared__ __align__(16) u16 sB[128 * 64];

    const int tid  = threadIdx.x;
    const int wave = tid >> 6, lane = tid & 63;
    const int wr = wave >> 1, wc = wave & 1;
    const int quad = lane >> 4, l15 = lane & 15;

    floatx4 acc[4][4];
    #pragma unroll
    for (int i = 0; i < 4; ++i)
        #pragma unroll
        for (int j = 0; j < 4; ++j)
            acc[i][j] = (floatx4){0.f, 0.f, 0.f, 0.f};

    #pragma unroll 1
    for (int kb = 0; kb < 16; ++kb) {
        __syncthreads();
        const int k0 = kb * 64;
        #pragma unroll
        for (int j = 0; j < 4; ++j) {
            int r  = wave * 32 + j * 8 + (lane >> 3);
            int kg = (lane & 7) ^ (r & 7);
            async16(A + (size_t)(m0 + r) * K + k0 + kg * 8, &sA[(wave * 32 + j * 8) * 64]);
            async16(W + (size_t)(n0 + r) * K + k0 + kg * 8, &sB[(wave * 32 + j * 8) * 64]);
        }
        __syncthreads();

        #pragma unroll
        for (int kk = 0; kk < 2; ++kk) {
            bf16x8 af[4], bf[4];
            const int kg = kk * 4 + quad;
            #pragma unroll
            for (int t = 0; t < 4; ++t) {
                int ra = wr * 64 + t * 16 + l15;
                af[t] = ld16B(&sA[ra * 64 + ((kg ^ (ra & 7)) * 8)]);
                int rb = wc * 64 + t * 16 + l15;
                bf[t] = ld16B(&sB[rb * 64 + ((kg ^ (rb & 7)) * 8)]);
            }
            #pragma unroll
            for (int mt = 0; mt < 4; ++mt)
                #pragma unroll
                for (int nt = 0; nt < 4; ++nt)
                    acc[mt][nt] = __builtin_amdgcn_mfma_f32_16x16x32_bf16(af[mt], bf[nt], acc[mt][nt], 0, 0, 0);
        }
    }

    // epilogue: C-layout col=lane&15, row=quad*4+r
    #pragma unroll
    for (int nt = 0; nt < 4; ++nt) {
        int col  = n0 + wc * 64 + nt * 16 + l15;
        float bv = bias[col];
        #pragma unroll
        for (int mt = 0; mt < 4; ++mt) {
            int row0 = m0 + wr * 64 + mt * 16 + quad * 4;
            if (MODE == 1) {
                // V^T: [b][h][d][t]; r=0..3 are consecutive t -> one 8B store
                float v0 = acc[mt][nt][0] + bv, v1 = acc[mt][nt][1] + bv;
                float v2 = acc[mt][nt][2] + bv, v3 = acc[mt][nt][3] + bv;
                u32 dws[2] = { pkbf(v0, v1), pkbf(v2, v3) };
                int b = row0 >> 11, t0 = row0 & 2047;
                size_t idx = (((size_t)(b * 16 + (col >> 6)) * 64 + (col & 63)) * 2048 + t0);
                __builtin_memcpy((u16*)out + idx, dws, 8);
            } else {
                #pragma unroll
                for (int r = 0; r < 4; ++r) {
                    int row = row0 + r;
                    float v = (acc[mt][nt][r] + bv) * scale;
                    if (MODE == 0) {
                        size_t idx = (((size_t)(row >> 11) * 16 + (col >> 6)) * 2048 + (row & 2047)) * 64 + (col & 63);
                        ((u16*)out)[idx] = f2b(v);
                    } else {
                        ((float*)out)[(size_t)row * 1024 + col] = v;
                    }
                }
            }
        }
    }
}

__global__ __launch_bounds__(256) void qk_kernel(
    const u16* __restrict__ x,
    const u16* __restrict__ Wq, const u16* __restrict__ Wk,
    const float* __restrict__ bq, const float* __restrict__ bk,
    u16* __restrict__ q, u16* __restrict__ k)
{
    const int z = blockIdx.z;
    gemm_bt_body<0, u16>(x, z ? Wk : Wq, z ? bk : bq, z ? k : q,
                         blockIdx.y * 128, blockIdx.x * 128, z ? 1.0f : QSCALE);
}

__global__ __launch_bounds__(256) void v_kernel(
    const u16* __restrict__ x, const u16* __restrict__ Wv,
    const float* __restrict__ bv, u16* __restrict__ vt)
{
    gemm_bt_body<1, u16>(x, Wv, bv, vt, blockIdx.y * 128, blockIdx.x * 128, 1.0f);
}

__global__ __launch_bounds__(256) void proj_kernel(
    const u16* __restrict__ y, const u16* __restrict__ Wo, const float* __restrict__ bo,
    float* __restrict__ out)
{
    gemm_bt_body<2, float>(y, Wo, bo, out, blockIdx.y * 128, blockIdx.x * 128, 1.0f);
}

// ---------------- Flash attention (no-max softmax; S^T/O^T orientation) ----------------
// grid (bh=64, qt=16), block 256 = 4 waves. Wave w: 32 Q rows (2 groups of 16).
// Q pre-scaled by 0.125*log2e, so P = exp2(S') directly.
__global__ __launch_bounds__(256, 4) void attn_kernel(
    const u16* __restrict__ Q, const u16* __restrict__ K,
    const u16* __restrict__ Vt, u16* __restrict__ Y)
{
    const int bh = blockIdx.x, qt = blockIdx.y;
    const int tid = threadIdx.x;
    const int wave = tid >> 6, lane = tid & 63;
    const int quad = lane >> 4, l15 = lane & 15;
    const int l7 = l15 & 7;

    __shared__ __align__(16) u16 sK[2][64 * 64];   // rows = tk-local, XOR-swizzled 8-u16 granules
    __shared__ __align__(16) u16 sVt[2][64 * 64];  // rows = d, cols = tk-local, same swizzle
    __shared__ __align__(16) u16 sP[4][16 * 64];   // per-wave, rows = qrow(16), 8B-granule swizzle

    const size_t base = (size_t)bh * (2048 * 64);

    // Q fragments (registers, whole kernel)
    bf16x8 qf[2][2];
    #pragma unroll
    for (int rg = 0; rg < 2; ++rg) {
        int qrow = qt * 128 + wave * 32 + rg * 16 + l15;
        const u16* qp = Q + base + (size_t)qrow * 64 + quad * 8;
        qf[rg][0] = ld16B(qp);
        qf[rg][1] = ld16B(qp + 32);
    }

    // staging source pointers (per lane): 8 rows per async16, 2 per buffer each
    const int r8 = lane >> 3, g7s = (lane & 7) ^ (lane >> 3);
    const u16* ksrc = K  + base + (size_t)(wave * 16 + r8) * 64   + g7s * 8;
    const u16* vsrc = Vt + base + (size_t)(wave * 16 + r8) * 2048 + g7s * 8;
    u16* dK0 = &sK[0][(wave * 16) * 64];
    u16* dV0 = &sVt[0][(wave * 16) * 64];

    floatx4 accO[2][4];
    #pragma unroll
    for (int rg = 0; rg < 2; ++rg)
        #pragma unroll
        for (int nt = 0; nt < 4; ++nt) accO[rg][nt] = (floatx4){0.f, 0.f, 0.f, 0.f};
    float rs[2] = {0.f, 0.f};

    // prologue: stage tile 0 into buf 0
    async16(ksrc,            dK0);
    async16(ksrc + 8 * 64,   dK0 + 8 * 64);
    async16(vsrc,            dV0);
    async16(vsrc + 8 * 2048, dV0 + 8 * 64);
    ksrc += 64 * 64; vsrc += 64;
    __syncthreads();

    #pragma unroll 1
    for (int kt = 0; kt < 32; ++kt) {
        const int cur = kt & 1;
        if (kt < 31) {
            u16* dK = &sK[cur ^ 1][(wave * 16) * 64];
            u16* dV = &sVt[cur ^ 1][(wave * 16) * 64];
            async16(ksrc,            dK);
            async16(ksrc + 8 * 64,   dK + 8 * 64);
            async16(vsrc,            dV);
            async16(vsrc + 8 * 2048, dV + 8 * 64);
            ksrc += 64 * 64; vsrc += 64;
        }
        const u16* bK = sK[cur];
        const u16* bV = sVt[cur];

        #pragma unroll
        for (int rg = 0; rg < 2; ++rg) {
            // S^T = K . Q  (C[m=kcol][n=qrow])
            floatx4 st[4];
            #pragma unroll
            for (int nt = 0; nt < 4; ++nt) st[nt] = (floatx4){0.f, 0.f, 0.f, 0.f};
            #pragma unroll
            for (int kk = 0; kk < 2; ++kk) {
                #pragma unroll
                for (int nt = 0; nt < 4; ++nt) {
                    bf16x8 kf = ld16B(&bK[(nt * 16 + l15) * 64 + (((kk * 4 + quad) ^ l7) * 8)]);
                    st[nt] = __builtin_amdgcn_mfma_f32_16x16x32_bf16(kf, qf[rg][kk], st[nt], 0, 0, 0);
                }
            }
            // P = exp2(S'), pack to bf16 pairs, wave-private LDS (swizzled b64)
            #pragma unroll
            for (int nt = 0; nt < 4; ++nt) {
                float p0 = __builtin_amdgcn_exp2f(st[nt][0]);
                float p1 = __builtin_amdgcn_exp2f(st[nt][1]);
                float p2 = __builtin_amdgcn_exp2f(st[nt][2]);
                float p3 = __builtin_amdgcn_exp2f(st[nt][3]);
                rs[rg] += (p0 + p1) + (p2 + p3);
                u32 dws[2] = { pkbf(p0, p1), pkbf(p2, p3) };
                int g8 = nt * 4 + quad;                      // 8B granule (4 u16)
                __builtin_memcpy((void*)&sP[wave][l15 * 64 + ((g8 ^ (2 * l7)) * 4)], dws, 8);
            }
            // O^T += V^T . P  (C[m=d][n=qrow]); DS pipe is in-order per wave
            #pragma unroll
            for (int kk = 0; kk < 2; ++kk) {
                bf16x8 pf = ld16B(&sP[wave][l15 * 64 + (((kk * 8 + quad * 2) ^ (2 * l7)) * 4)]);
                #pragma unroll
                for (int nt = 0; nt < 4; ++nt) {
                    bf16x8 vf = ld16B(&bV[(nt * 16 + l15) * 64 + (((kk * 4 + quad) ^ l7) * 8)]);
                    accO[rg][nt] = __builtin_amdgcn_mfma_f32_16x16x32_bf16(vf, pf, accO[rg][nt], 0, 0, 0);
                }
            }
        }
        __syncthreads();
    }

    // epilogue: reduce row sums across quads, normalize, store Y[b][t][h*64+d]
    const int b = bh >> 4, h = bh & 15;
    #pragma unroll
    for (int rg = 0; rg < 2; ++rg) {
        float s = rs[rg];
        s += __shfl_xor(s, 16);
        s += __shfl_xor(s, 32);
        float inv = 1.f / s;
        int t = qt * 128 + wave * 32 + rg * 16 + l15;
        size_t rowbase = ((size_t)(b * 2048 + t)) * 1024 + h * 64;
        #pragma unroll
        for (int nt = 0; nt < 4; ++nt) {
            u32 dws[2] = { pkbf(accO[rg][nt][0] * inv, accO[rg][nt][1] * inv),
                           pkbf(accO[rg][nt][2] * inv, accO[rg][nt][3] * inv) };
            __builtin_memcpy(&Y[rowbase + nt * 16 + quad * 4], dws, 8);
        }
    }
}

// ---------------- launch ----------------
extern "C" void kernel_launch(void* const* d_in, const int* in_sizes, int n_in,
                              void* d_out, int out_size, void* d_ws, size_t ws_size,
                              hipStream_t stream)
{
    const float* x  = (const float*)d_in[0];
    const float* Wq = (const float*)d_in[1];
    const float* bq = (const float*)d_in[2];
    const float* Wk = (const float*)d_in[3];
    const float* bk = (const float*)d_in[4];
    const float* Wv = (const float*)d_in[5];
    const float* bv = (const float*)d_in[6];
    const float* Wo = (const float*)d_in[7];
    const float* bo = (const float*)d_in[8];
    float* out = (float*)d_out;

    const size_t NTOK = (size_t)8192 * 1024;
    const size_t WN   = (size_t)1024 * 1024;
    u16* xb  = (u16*)d_ws;
    u16* wqb = xb + NTOK;
    u16* wkb = wqb + WN;
    u16* wvb = wkb + WN;
    u16* wob = wvb + WN;
    u16* q   = wob + WN;
    u16* k   = q + NTOK;
    u16* vt  = k + NTOK;
    u16* y   = vt + NTOK;

    convert_kernel<<<dim3(12288), 256, 0, stream>>>(x, Wq, Wk, Wv, Wo, xb, wqb, wkb, wvb, wob);
    qk_kernel<<<dim3(8, 64, 2), 256, 0, stream>>>(xb, wqb, wkb, bq, bk, q, k);
    v_kernel<<<dim3(8, 64), 256, 0, stream>>>(xb, wvb, bv, vt);
    attn_kernel<<<dim3(64, 16), 256, 0, stream>>>(q, k, vt, y);
    proj_kernel<<<dim3(8, 64), 256, 0, stream>>>(y, wob, bo, out);
}

// Round 4
// 276.302 us; speedup vs baseline: 1.5220x; 1.1635x over previous
//
#include <hip/hip_runtime.h>
#include <stdint.h>

// B=4, T=2048, C=1024, H=16, D=64.
// Inputs/outputs FP32 (per reference). Internal: bf16 MFMA, fp32 accum.

using u16 = unsigned short;
using u32 = unsigned int;
typedef __attribute__((ext_vector_type(8))) __bf16 bf16x8;
typedef __attribute__((ext_vector_type(4))) float  floatx4;

#define QSCALE 0.18033688011112043f   // 0.125 * log2(e), folded into Q projection

__device__ __forceinline__ u16 f2b(float f) {
    union { float f; u32 i; } x; x.f = f;
    return (u16)((x.i + 0x7fffu + ((x.i >> 16) & 1u)) >> 16);
}
__device__ __forceinline__ u32 fbits(float f) { union { float f; u32 i; } x; x.f = f; return x.i; }
// pack two fp32 -> (bf16(b)<<16)|bf16(a) : 2 adds + 1 v_perm
__device__ __forceinline__ u32 pkbf(float a, float b) {
    u32 ia = fbits(a) + 0x8000u, ib = fbits(b) + 0x8000u;
    return __builtin_amdgcn_perm(ib, ia, 0x07060302u);
}
__device__ __forceinline__ bf16x8 ld16B(const u16* p) {
    bf16x8 v; __builtin_memcpy(&v, p, 16); return v;
}
__device__ __forceinline__ void async16(const u16* g, u16* l) {
    __builtin_amdgcn_global_load_lds((const __attribute__((address_space(1))) unsigned int*)g,
                                     (__attribute__((address_space(3))) unsigned int*)l,
                                     16, 0, 0);
}

// ---------------- convert fp32 -> bf16 (x + 4 weight matrices) ----------------
__global__ __launch_bounds__(256) void convert_kernel(
    const float* __restrict__ x,
    const float* __restrict__ Wq, const float* __restrict__ Wk,
    const float* __restrict__ Wv, const float* __restrict__ Wo,
    u16* __restrict__ xb, u16* __restrict__ wqb, u16* __restrict__ wkb,
    u16* __restrict__ wvb, u16* __restrict__ wob)
{
    size_t e = ((size_t)blockIdx.x * 256 + threadIdx.x) * 4;
    const float* src; u16* dst; size_t off;
    const size_t XN = (size_t)8 << 20;
    if (e < XN) { src = x; dst = xb; off = e; }
    else {
        size_t k = e - XN;
        int w = (int)(k >> 20);
        off = k & ((1u << 20) - 1);
        src = (w == 0) ? Wq : (w == 1) ? Wk : (w == 2) ? Wv : Wo;
        dst = (w == 0) ? wqb : (w == 1) ? wkb : (w == 2) ? wvb : wob;
    }
    float4 f = *(const float4*)(src + off);
    u32 dws[2] = { pkbf(f.x, f.y), pkbf(f.z, f.w) };
    __builtin_memcpy(dst + off, dws, 8);
}

// ---------------- GEMM: C[m,n] = A[m,:].W[n,:] + bias + epilogue ----------------
// MODE 0: u16 out, row-major [M,1024], value*(scale) (Q/K; bias by col)
// MODE 1: u16 out, Vt layout: m=c (h*64+d), n=tg (b*2048+t); bias by ROW
// MODE 2: f32 out, row-major [M,1024] (final projection; bias by col)
template <int MODE, typename OutT>
__device__ __forceinline__ void gemm_bt_body(const u16* __restrict__ A,
                                             const u16* __restrict__ W,
                                             const float* __restrict__ bias,
                                             OutT* __restrict__ out,
                                             int m0, int n0, float scale)
{
    constexpr int K = 1024;
    __shared__ __align__(16) u16 sA[128 * 64];
    __shared__ __align__(16) u16 sB[128 * 64];

    const int tid  = threadIdx.x;
    const int wave = tid >> 6, lane = tid & 63;
    const int wr = wave >> 1, wc = wave & 1;
    const int quad = lane >> 4, l15 = lane & 15;

    floatx4 acc[4][4];
    #pragma unroll
    for (int i = 0; i < 4; ++i)
        #pragma unroll
        for (int j = 0; j < 4; ++j)
            acc[i][j] = (floatx4){0.f, 0.f, 0.f, 0.f};

    #pragma unroll 1
    for (int kb = 0; kb < 16; ++kb) {
        __syncthreads();
        const int k0 = kb * 64;
        #pragma unroll
        for (int j = 0; j < 4; ++j) {
            int r  = wave * 32 + j * 8 + (lane >> 3);
            int kg = (lane & 7) ^ (r & 7);
            async16(A + (size_t)(m0 + r) * K + k0 + kg * 8, &sA[(wave * 32 + j * 8) * 64]);
            async16(W + (size_t)(n0 + r) * K + k0 + kg * 8, &sB[(wave * 32 + j * 8) * 64]);
        }
        __syncthreads();

        #pragma unroll
        for (int kk = 0; kk < 2; ++kk) {
            bf16x8 af[4], bf[4];
            const int kg = kk * 4 + quad;
            #pragma unroll
            for (int t = 0; t < 4; ++t) {
                int ra = wr * 64 + t * 16 + l15;
                af[t] = ld16B(&sA[ra * 64 + ((kg ^ (ra & 7)) * 8)]);
                int rb = wc * 64 + t * 16 + l15;
                bf[t] = ld16B(&sB[rb * 64 + ((kg ^ (rb & 7)) * 8)]);
            }
            #pragma unroll
            for (int mt = 0; mt < 4; ++mt)
                #pragma unroll
                for (int nt = 0; nt < 4; ++nt)
                    acc[mt][nt] = __builtin_amdgcn_mfma_f32_16x16x32_bf16(af[mt], bf[nt], acc[mt][nt], 0, 0, 0);
        }
    }

    // epilogue: C layout col=lane&15, row=quad*4+r
    #pragma unroll
    for (int nt = 0; nt < 4; ++nt) {
        int col = n0 + wc * 64 + nt * 16 + l15;
        float bcol = (MODE == 1) ? 0.f : bias[col];
        #pragma unroll
        for (int mt = 0; mt < 4; ++mt) {
            #pragma unroll
            for (int r = 0; r < 4; ++r) {
                int row = m0 + wr * 64 + mt * 16 + quad * 4 + r;
                if (MODE == 1) {
                    // row = c (h*64+d), col = tg (b*2048+t)
                    float v = acc[mt][nt][r] + bias[row];
                    size_t idx = (((size_t)((col >> 11) * 16 + (row >> 6)) * 64 + (row & 63)) * 2048) + (col & 2047);
                    ((u16*)out)[idx] = f2b(v);
                } else if (MODE == 0) {
                    float v = (acc[mt][nt][r] + bcol) * scale;
                    ((u16*)out)[(size_t)row * 1024 + col] = f2b(v);
                } else {
                    ((float*)out)[(size_t)row * 1024 + col] = acc[mt][nt][r] + bcol;
                }
            }
        }
    }
}

__global__ __launch_bounds__(256) void qk_kernel(
    const u16* __restrict__ x,
    const u16* __restrict__ Wq, const u16* __restrict__ Wk,
    const float* __restrict__ bq, const float* __restrict__ bk,
    u16* __restrict__ q, u16* __restrict__ k)
{
    const int z = blockIdx.z;
    gemm_bt_body<0, u16>(x, z ? Wk : Wq, z ? bk : bq, z ? k : q,
                         blockIdx.y * 128, blockIdx.x * 128, z ? 1.0f : QSCALE);
}

// V^T = Wv . x^T : A = Wv (M=1024 rows=c), B = x (N=8192 rows=tg)
__global__ __launch_bounds__(256) void v_kernel(
    const u16* __restrict__ x, const u16* __restrict__ Wv,
    const float* __restrict__ bv, u16* __restrict__ vt)
{
    gemm_bt_body<1, u16>(Wv, x, bv, vt, blockIdx.y * 128, blockIdx.x * 128, 1.0f);
}

__global__ __launch_bounds__(256) void proj_kernel(
    const u16* __restrict__ y, const u16* __restrict__ Wo, const float* __restrict__ bo,
    float* __restrict__ out)
{
    gemm_bt_body<2, float>(y, Wo, bo, out, blockIdx.y * 128, blockIdx.x * 128, 1.0f);
}

// ---------------- Flash attention (no-max softmax; S^T/O^T orientation) ----------------
// grid (bh=64, qt=8), block 256 = 4 waves. Wave owns 64 q-rows (4 n-tiles of 16).
// Q row-major [8192,1024] pre-scaled by 0.125*log2e; K row-major; Vt [bh*64+d, 2048].
__global__ __launch_bounds__(256, 2) void attn_kernel(
    const u16* __restrict__ Q, const u16* __restrict__ K,
    const u16* __restrict__ Vt, u16* __restrict__ Y)
{
    const int bh = blockIdx.x, qt = blockIdx.y;
    const int tid = threadIdx.x;
    const int wave = tid >> 6, lane = tid & 63;
    const int quad = lane >> 4, l15 = lane & 15, l7 = l15 & 7;
    const int b = bh >> 4, h = bh & 15;

    __shared__ __align__(16) u16 sK[2][64 * 64];   // [tk-local][d], XOR-swizzled 16B granules
    __shared__ __align__(16) u16 sV[2][64 * 64];   // [d][tk-local], same swizzle
    __shared__ __align__(16) u16 sP[4][64 * 72];   // per-wave [q-local][kcol], stride 72 (bank-safe)

    // Q B-fragments (registers, whole kernel): qf[nt][kk]
    bf16x8 qf[4][2];
    #pragma unroll
    for (int nt = 0; nt < 4; ++nt) {
        const u16* qp = Q + (size_t)(b * 2048 + qt * 256 + wave * 64 + nt * 16 + l15) * 1024 + h * 64 + quad * 8;
        qf[nt][0] = ld16B(qp);
        qf[nt][1] = ld16B(qp + 32);
    }

    // staging: per wave 16 rows of K and of V per tile (2 async16 each)
    const int r8 = lane >> 3;
    const int g7 = (lane & 7) ^ r8;
    const u16* ksrc = K  + (size_t)(b * 2048 + wave * 16 + r8) * 1024 + h * 64 + g7 * 8;
    const u16* vsrc = Vt + ((size_t)(bh * 64 + wave * 16 + r8)) * 2048 + g7 * 8;

    floatx4 accO[4][4];
    #pragma unroll
    for (int mt = 0; mt < 4; ++mt)
        #pragma unroll
        for (int nt = 0; nt < 4; ++nt) accO[mt][nt] = (floatx4){0.f, 0.f, 0.f, 0.f};
    float rs[4] = {0.f, 0.f, 0.f, 0.f};

    // prologue: stage tile 0 into buf 0
    {
        u16* dK = &sK[0][wave * 16 * 64];
        u16* dV = &sV[0][wave * 16 * 64];
        async16(ksrc,            dK);
        async16(ksrc + 8 * 1024, dK + 8 * 64);
        async16(vsrc,            dV);
        async16(vsrc + 8 * 2048, dV + 8 * 64);
    }
    __syncthreads();

    #pragma unroll 1
    for (int kt = 0; kt < 32; ++kt) {
        const int cur = kt & 1;
        if (kt < 31) {
            u16* dK = &sK[cur ^ 1][wave * 16 * 64];
            u16* dV = &sV[cur ^ 1][wave * 16 * 64];
            const u16* ks = ksrc + (size_t)(kt + 1) * 64 * 1024;
            const u16* vs = vsrc + (size_t)(kt + 1) * 64;
            async16(ks,            dK);
            async16(ks + 8 * 1024, dK + 8 * 64);
            async16(vs,            dV);
            async16(vs + 8 * 2048, dV + 8 * 64);
        }
        const u16* bK = sK[cur];
        const u16* bV = sV[cur];
        u16* sp = sP[wave];

        // K A-fragments, read tile ONCE per wave, reused across 4 n-tiles
        bf16x8 kf[4][2];
        #pragma unroll
        for (int mt = 0; mt < 4; ++mt)
            #pragma unroll
            for (int kk = 0; kk < 2; ++kk)
                kf[mt][kk] = ld16B(&bK[(mt * 16 + l15) * 64 + (((kk * 4 + quad) ^ l7) * 8)]);

        // S^T = K.Q per n-tile; exp2; pack to sP[q][kcol]
        #pragma unroll
        for (int nt = 0; nt < 4; ++nt) {
            floatx4 st[4];
            #pragma unroll
            for (int mt = 0; mt < 4; ++mt) st[mt] = (floatx4){0.f, 0.f, 0.f, 0.f};
            #pragma unroll
            for (int kk = 0; kk < 2; ++kk)
                #pragma unroll
                for (int mt = 0; mt < 4; ++mt)
                    st[mt] = __builtin_amdgcn_mfma_f32_16x16x32_bf16(kf[mt][kk], qf[nt][kk], st[mt], 0, 0, 0);
            #pragma unroll
            for (int mt = 0; mt < 4; ++mt) {
                float p0 = __builtin_amdgcn_exp2f(st[mt][0]);
                float p1 = __builtin_amdgcn_exp2f(st[mt][1]);
                float p2 = __builtin_amdgcn_exp2f(st[mt][2]);
                float p3 = __builtin_amdgcn_exp2f(st[mt][3]);
                rs[nt] += (p0 + p1) + (p2 + p3);
                u32 dws[2] = { pkbf(p0, p1), pkbf(p2, p3) };
                __builtin_memcpy(&sp[(nt * 16 + l15) * 72 + mt * 16 + quad * 4], dws, 8);
            }
        }

        // O^T += Vt.P
        #pragma unroll
        for (int kk = 0; kk < 2; ++kk) {
            bf16x8 pf[4];
            #pragma unroll
            for (int nt = 0; nt < 4; ++nt)
                pf[nt] = ld16B(&sp[(nt * 16 + l15) * 72 + kk * 32 + quad * 8]);
            #pragma unroll
            for (int mt = 0; mt < 4; ++mt) {
                bf16x8 vf = ld16B(&bV[(mt * 16 + l15) * 64 + (((kk * 4 + quad) ^ l7) * 8)]);
                #pragma unroll
                for (int nt = 0; nt < 4; ++nt)
                    accO[mt][nt] = __builtin_amdgcn_mfma_f32_16x16x32_bf16(vf, pf[nt], accO[mt][nt], 0, 0, 0);
            }
        }
        __syncthreads();
    }

    // epilogue: normalize, transpose O^T->O via sP, coalesced 128B-row stores
    float inv[4];
    #pragma unroll
    for (int nt = 0; nt < 4; ++nt) {
        float s = rs[nt];
        s += __shfl_xor(s, 16);
        s += __shfl_xor(s, 32);
        inv[nt] = 1.f / s;
    }
    u16* sp = sP[wave];
    #pragma unroll
    for (int nt = 0; nt < 4; ++nt)
        #pragma unroll
        for (int mt = 0; mt < 4; ++mt) {
            u32 dws[2] = { pkbf(accO[mt][nt][0] * inv[nt], accO[mt][nt][1] * inv[nt]),
                           pkbf(accO[mt][nt][2] * inv[nt], accO[mt][nt][3] * inv[nt]) };
            __builtin_memcpy(&sp[(nt * 16 + l15) * 72 + mt * 16 + quad * 4], dws, 8);
        }
    const int rl = lane >> 3, cl = lane & 7;
    #pragma unroll
    for (int pass = 0; pass < 8; ++pass) {
        int q = pass * 8 + rl;
        int t = qt * 256 + wave * 64 + q;
        bf16x8 vrow = ld16B(&sp[q * 72 + cl * 8]);
        __builtin_memcpy(Y + ((size_t)(b * 2048 + t)) * 1024 + h * 64 + cl * 8, &vrow, 16);
    }
}

// ---------------- launch ----------------
extern "C" void kernel_launch(void* const* d_in, const int* in_sizes, int n_in,
                              void* d_out, int out_size, void* d_ws, size_t ws_size,
                              hipStream_t stream)
{
    const float* x  = (const float*)d_in[0];
    const float* Wq = (const float*)d_in[1];
    const float* bq = (const float*)d_in[2];
    const float* Wk = (const float*)d_in[3];
    const float* bk = (const float*)d_in[4];
    const float* Wv = (const float*)d_in[5];
    const float* bv = (const float*)d_in[6];
    const float* Wo = (const float*)d_in[7];
    const float* bo = (const float*)d_in[8];
    float* out = (float*)d_out;

    const size_t NTOK = (size_t)8192 * 1024;
    const size_t WN   = (size_t)1024 * 1024;
    u16* xb  = (u16*)d_ws;
    u16* wqb = xb + NTOK;
    u16* wkb = wqb + WN;
    u16* wvb = wkb + WN;
    u16* wob = wvb + WN;
    u16* q   = wob + WN;
    u16* k   = q + NTOK;
    u16* vt  = k + NTOK;
    u16* y   = vt + NTOK;

    convert_kernel<<<dim3(12288), 256, 0, stream>>>(x, Wq, Wk, Wv, Wo, xb, wqb, wkb, wvb, wob);
    qk_kernel<<<dim3(8, 64, 2), 256, 0, stream>>>(xb, wqb, wkb, bq, bk, q, k);
    v_kernel<<<dim3(64, 8), 256, 0, stream>>>(xb, wvb, bv, vt);
    attn_kernel<<<dim3(64, 8), 256, 0, stream>>>(q, k, vt, y);
    proj_kernel<<<dim3(8, 64), 256, 0, stream>>>(y, wob, bo, out);
}

// Round 5
// 269.006 us; speedup vs baseline: 1.5632x; 1.0271x over previous
//
#include <hip/hip_runtime.h>
#include <stdint.h>

// B=4, T=2048, C=1024, H=16, D=64.
// Inputs/outputs FP32 (per reference). Internal: bf16 MFMA, fp32 accum.

using u16 = unsigned short;
using u32 = unsigned int;
typedef __attribute__((ext_vector_type(8))) __bf16 bf16x8;
typedef __attribute__((ext_vector_type(4))) float  floatx4;

#define QSCALE 0.18033688011112043f   // 0.125 * log2(e), folded into Q projection

__device__ __forceinline__ u16 f2b(float f) {
    union { float f; u32 i; } x; x.f = f;
    return (u16)((x.i + 0x7fffu + ((x.i >> 16) & 1u)) >> 16);
}
__device__ __forceinline__ u32 fbits(float f) { union { float f; u32 i; } x; x.f = f; return x.i; }
// pack two fp32 -> (bf16(b)<<16)|bf16(a) : 2 adds + 1 v_perm
__device__ __forceinline__ u32 pkbf(float a, float b) {
    u32 ia = fbits(a) + 0x8000u, ib = fbits(b) + 0x8000u;
    return __builtin_amdgcn_perm(ib, ia, 0x07060302u);
}
__device__ __forceinline__ bf16x8 ld16B(const u16* p) {
    bf16x8 v; __builtin_memcpy(&v, p, 16); return v;
}
__device__ __forceinline__ void async16(const u16* g, u16* l) {
    __builtin_amdgcn_global_load_lds((const __attribute__((address_space(1))) unsigned int*)g,
                                     (__attribute__((address_space(3))) unsigned int*)l,
                                     16, 0, 0);
}

// ---------------- convert fp32 -> bf16 (x + 4 weight matrices) ----------------
__global__ __launch_bounds__(256) void convert_kernel(
    const float* __restrict__ x,
    const float* __restrict__ Wq, const float* __restrict__ Wk,
    const float* __restrict__ Wv, const float* __restrict__ Wo,
    u16* __restrict__ xb, u16* __restrict__ wqb, u16* __restrict__ wkb,
    u16* __restrict__ wvb, u16* __restrict__ wob)
{
    size_t e = ((size_t)blockIdx.x * 256 + threadIdx.x) * 4;
    const float* src; u16* dst; size_t off;
    const size_t XN = (size_t)8 << 20;
    if (e < XN) { src = x; dst = xb; off = e; }
    else {
        size_t k = e - XN;
        int w = (int)(k >> 20);
        off = k & ((1u << 20) - 1);
        src = (w == 0) ? Wq : (w == 1) ? Wk : (w == 2) ? Wv : Wo;
        dst = (w == 0) ? wqb : (w == 1) ? wkb : (w == 2) ? wvb : wob;
    }
    float4 f = *(const float4*)(src + off);
    u32 dws[2] = { pkbf(f.x, f.y), pkbf(f.z, f.w) };
    __builtin_memcpy(dst + off, dws, 8);
}

// ---------------- shared GEMM K-loop: acc = A[128 rows m0..] . W[128 rows n0..]^T ----------------
// K=1024, BK=64, 4 waves each 64x64, XOR-swizzled LDS granules.
__device__ __forceinline__ void gemm_loop(const u16* __restrict__ A, const u16* __restrict__ W,
                                          int m0, int n0, floatx4 (&acc)[4][4],
                                          u16* __restrict__ sA, u16* __restrict__ sB)
{
    constexpr int K = 1024;
    const int tid  = threadIdx.x;
    const int wave = tid >> 6, lane = tid & 63;
    const int wr = wave >> 1, wc = wave & 1;
    const int quad = lane >> 4, l15 = lane & 15;

    #pragma unroll
    for (int i = 0; i < 4; ++i)
        #pragma unroll
        for (int j = 0; j < 4; ++j)
            acc[i][j] = (floatx4){0.f, 0.f, 0.f, 0.f};

    #pragma unroll 1
    for (int kb = 0; kb < 16; ++kb) {
        __syncthreads();
        const int k0 = kb * 64;
        #pragma unroll
        for (int j = 0; j < 4; ++j) {
            int r  = wave * 32 + j * 8 + (lane >> 3);
            int kg = (lane & 7) ^ (r & 7);
            async16(A + (size_t)(m0 + r) * K + k0 + kg * 8, &sA[(wave * 32 + j * 8) * 64]);
            async16(W + (size_t)(n0 + r) * K + k0 + kg * 8, &sB[(wave * 32 + j * 8) * 64]);
        }
        __syncthreads();

        #pragma unroll
        for (int kk = 0; kk < 2; ++kk) {
            bf16x8 af[4], bf[4];
            const int kg = kk * 4 + quad;
            #pragma unroll
            for (int t = 0; t < 4; ++t) {
                int ra = wr * 64 + t * 16 + l15;
                af[t] = ld16B(&sA[ra * 64 + ((kg ^ (ra & 7)) * 8)]);
                int rb = wc * 64 + t * 16 + l15;
                bf[t] = ld16B(&sB[rb * 64 + ((kg ^ (rb & 7)) * 8)]);
            }
            #pragma unroll
            for (int mt = 0; mt < 4; ++mt)
                #pragma unroll
                for (int nt = 0; nt < 4; ++nt)
                    acc[mt][nt] = __builtin_amdgcn_mfma_f32_16x16x32_bf16(af[mt], bf[nt], acc[mt][nt], 0, 0, 0);
        }
    }
}

// ---------------- fused QKV projection ----------------
// Wcat = [3072,1024] (Wq;Wk;Wv rows contiguous in ws). grid (24, 64).
// z=0: Q row-major * QSCALE; z=1: K row-major; z=2: Vt [bh*64+d][2048].
__global__ __launch_bounds__(256) void qkv_kernel(
    const u16* __restrict__ x, const u16* __restrict__ Wcat,
    const float* __restrict__ bq, const float* __restrict__ bk, const float* __restrict__ bv,
    u16* __restrict__ q, u16* __restrict__ k, u16* __restrict__ vt)
{
    __shared__ __align__(16) u16 sA[128 * 64];
    __shared__ __align__(16) u16 sB[128 * 64];
    const int m0 = blockIdx.y * 128, n0 = blockIdx.x * 128;
    floatx4 acc[4][4];
    gemm_loop(x, Wcat, m0, n0, acc, sA, sB);

    const int tid = threadIdx.x;
    const int wave = tid >> 6, lane = tid & 63;
    const int wr = wave >> 1, wc = wave & 1;
    const int quad = lane >> 4, l15 = lane & 15;

    const int z = n0 >> 10;
    const float* bb = (z == 0) ? bq : (z == 1) ? bk : bv;
    const float scale = (z == 0) ? QSCALE : 1.0f;
    u16* o = (z == 0) ? q : k;

    #pragma unroll
    for (int nt = 0; nt < 4; ++nt) {
        int col  = n0 + wc * 64 + nt * 16 + l15;   // in [0,3072)
        int c    = col & 1023;
        float bv_ = bb[c];
        #pragma unroll
        for (int mt = 0; mt < 4; ++mt) {
            int row0 = m0 + wr * 64 + mt * 16 + quad * 4;
            if (z == 2) {
                // Vt: addr = ((b*16+h)*64+d)*2048 + t, t=row contiguous -> 8B store
                float v0 = acc[mt][nt][0] + bv_, v1 = acc[mt][nt][1] + bv_;
                float v2 = acc[mt][nt][2] + bv_, v3 = acc[mt][nt][3] + bv_;
                u32 dws[2] = { pkbf(v0, v1), pkbf(v2, v3) };
                int b = row0 >> 11, t0 = row0 & 2047;
                size_t idx = ((size_t)((b * 16 + (c >> 6)) * 64 + (c & 63)) * 2048) + t0;
                __builtin_memcpy(vt + idx, dws, 8);
            } else {
                #pragma unroll
                for (int r = 0; r < 4; ++r) {
                    float v = (acc[mt][nt][r] + bv_) * scale;
                    o[(size_t)(row0 + r) * 1024 + c] = f2b(v);
                }
            }
        }
    }
}

// ---------------- output projection ----------------
__global__ __launch_bounds__(256) void proj_kernel(
    const u16* __restrict__ y, const u16* __restrict__ Wo, const float* __restrict__ bo,
    float* __restrict__ out)
{
    __shared__ __align__(16) u16 sA[128 * 64];
    __shared__ __align__(16) u16 sB[128 * 64];
    const int m0 = blockIdx.y * 128, n0 = blockIdx.x * 128;
    floatx4 acc[4][4];
    gemm_loop(y, Wo, m0, n0, acc, sA, sB);

    const int tid = threadIdx.x;
    const int wave = tid >> 6, lane = tid & 63;
    const int wr = wave >> 1, wc = wave & 1;
    const int quad = lane >> 4, l15 = lane & 15;

    #pragma unroll
    for (int nt = 0; nt < 4; ++nt) {
        int col = n0 + wc * 64 + nt * 16 + l15;
        float bv_ = bo[col];
        #pragma unroll
        for (int mt = 0; mt < 4; ++mt) {
            int row0 = m0 + wr * 64 + mt * 16 + quad * 4;
            #pragma unroll
            for (int r = 0; r < 4; ++r)
                out[(size_t)(row0 + r) * 1024 + col] = acc[mt][nt][r] + bv_;
        }
    }
}

// ---------------- Flash attention (no-max softmax; S^T/O^T; per-nt fused pipeline) ----------------
// grid (bh=64, qt=8), block 256 = 4 waves. Wave owns 64 q-rows (4 n-tiles of 16).
// Q row-major [8192,1024] pre-scaled by 0.125*log2e; K row-major; Vt [bh*64+d, 2048].
__global__ __launch_bounds__(256, 2) void attn_kernel(
    const u16* __restrict__ Q, const u16* __restrict__ K,
    const u16* __restrict__ Vt, u16* __restrict__ Y)
{
    const int bh = blockIdx.x, qt = blockIdx.y;
    const int tid = threadIdx.x;
    const int wave = tid >> 6, lane = tid & 63;
    const int quad = lane >> 4, l15 = lane & 15, l7 = l15 & 7;
    const int b = bh >> 4, h = bh & 15;

    __shared__ __align__(16) u16 sK[2][64 * 64];   // [tk-local][d], XOR-swizzled 16B granules
    __shared__ __align__(16) u16 sV[2][64 * 64];   // [d][tk-local], same swizzle
    __shared__ __align__(16) u16 sP[4][64 * 72];   // per-wave [q-local][kcol], stride 72

    const __bf16 one = (__bf16)1.0f;
    const bf16x8 ones = { one, one, one, one, one, one, one, one };

    // Q B-fragments (registers, whole kernel): qf[nt][kk]
    bf16x8 qf[4][2];
    #pragma unroll
    for (int nt = 0; nt < 4; ++nt) {
        const u16* qp = Q + (size_t)(b * 2048 + qt * 256 + wave * 64 + nt * 16 + l15) * 1024 + h * 64 + quad * 8;
        qf[nt][0] = ld16B(qp);
        qf[nt][1] = ld16B(qp + 32);
    }

    const int r8 = lane >> 3;
    const int g7 = (lane & 7) ^ r8;
    const u16* ksrc = K  + (size_t)(b * 2048 + wave * 16 + r8) * 1024 + h * 64 + g7 * 8;
    const u16* vsrc = Vt + ((size_t)(bh * 64 + wave * 16 + r8)) * 2048 + g7 * 8;

    floatx4 accO[4][4];
    #pragma unroll
    for (int mt = 0; mt < 4; ++mt)
        #pragma unroll
        for (int nt = 0; nt < 4; ++nt) accO[mt][nt] = (floatx4){0.f, 0.f, 0.f, 0.f};
    floatx4 accR[4];   // row sums via ones-row MFMA (C cols = q, all rows identical)
    #pragma unroll
    for (int nt = 0; nt < 4; ++nt) accR[nt] = (floatx4){0.f, 0.f, 0.f, 0.f};

    // prologue: stage tile 0 into buf 0
    {
        u16* dK = &sK[0][wave * 16 * 64];
        u16* dV = &sV[0][wave * 16 * 64];
        async16(ksrc,            dK);
        async16(ksrc + 8 * 1024, dK + 8 * 64);
        async16(vsrc,            dV);
        async16(vsrc + 8 * 2048, dV + 8 * 64);
    }
    __syncthreads();

    u16* sp = sP[wave];
    const int spRow = l15 * 72;   // within this wave's nt-block of rows

    #pragma unroll 1
    for (int kt = 0; kt < 32; ++kt) {
        const int cur = kt & 1;
        if (kt < 31) {
            u16* dK = &sK[cur ^ 1][wave * 16 * 64];
            u16* dV = &sV[cur ^ 1][wave * 16 * 64];
            const u16* ks = ksrc + (size_t)(kt + 1) * 64 * 1024;
            const u16* vs = vsrc + (size_t)(kt + 1) * 64;
            async16(ks,            dK);
            async16(ks + 8 * 1024, dK + 8 * 64);
            async16(vs,            dV);
            async16(vs + 8 * 2048, dV + 8 * 64);
        }
        const u16* bK = sK[cur];
        const u16* bV = sV[cur];

        // hoist all K and V fragments (tile read once per wave)
        bf16x8 kf[4][2], vf[4][2];
        #pragma unroll
        for (int mt = 0; mt < 4; ++mt)
            #pragma unroll
            for (int kk = 0; kk < 2; ++kk) {
                kf[mt][kk] = ld16B(&bK[(mt * 16 + l15) * 64 + (((kk * 4 + quad) ^ l7) * 8)]);
                vf[mt][kk] = ld16B(&bV[(mt * 16 + l15) * 64 + (((kk * 4 + quad) ^ l7) * 8)]);
            }

        // fused per-nt pipeline: S^T -> exp2 -> pack -> PV (+ row-sum via ones MFMA)
        #pragma unroll
        for (int nt = 0; nt < 4; ++nt) {
            floatx4 st[4];
            #pragma unroll
            for (int mt = 0; mt < 4; ++mt) st[mt] = (floatx4){0.f, 0.f, 0.f, 0.f};
            #pragma unroll
            for (int kk = 0; kk < 2; ++kk)
                #pragma unroll
                for (int mt = 0; mt < 4; ++mt)
                    st[mt] = __builtin_amdgcn_mfma_f32_16x16x32_bf16(kf[mt][kk], qf[nt][kk], st[mt], 0, 0, 0);

            u16* spn = sp + nt * 16 * 72 + spRow;
            #pragma unroll
            for (int mt = 0; mt < 4; ++mt) {
                float p0 = __builtin_amdgcn_exp2f(st[mt][0]);
                float p1 = __builtin_amdgcn_exp2f(st[mt][1]);
                float p2 = __builtin_amdgcn_exp2f(st[mt][2]);
                float p3 = __builtin_amdgcn_exp2f(st[mt][3]);
                u32 dws[2] = { pkbf(p0, p1), pkbf(p2, p3) };
                __builtin_memcpy(spn + mt * 16 + quad * 4, dws, 8);
            }
            bf16x8 pf0 = ld16B(spn + quad * 8);
            bf16x8 pf1 = ld16B(spn + 32 + quad * 8);
            accR[nt] = __builtin_amdgcn_mfma_f32_16x16x32_bf16(ones, pf0, accR[nt], 0, 0, 0);
            accR[nt] = __builtin_amdgcn_mfma_f32_16x16x32_bf16(ones, pf1, accR[nt], 0, 0, 0);
            #pragma unroll
            for (int mt = 0; mt < 4; ++mt) {
                accO[mt][nt] = __builtin_amdgcn_mfma_f32_16x16x32_bf16(vf[mt][0], pf0, accO[mt][nt], 0, 0, 0);
                accO[mt][nt] = __builtin_amdgcn_mfma_f32_16x16x32_bf16(vf[mt][1], pf1, accO[mt][nt], 0, 0, 0);
            }
        }
        __syncthreads();
    }

    // epilogue: normalize (accR already complete across quads), transpose via sP, 16B stores
    float inv[4];
    #pragma unroll
    for (int nt = 0; nt < 4; ++nt) inv[nt] = 1.f / accR[nt][0];
    #pragma unroll
    for (int nt = 0; nt < 4; ++nt)
        #pragma unroll
        for (int mt = 0; mt < 4; ++mt) {
            u32 dws[2] = { pkbf(accO[mt][nt][0] * inv[nt], accO[mt][nt][1] * inv[nt]),
                           pkbf(accO[mt][nt][2] * inv[nt], accO[mt][nt][3] * inv[nt]) };
            __builtin_memcpy(&sp[(nt * 16 + l15) * 72 + mt * 16 + quad * 4], dws, 8);
        }
    const int rl = lane >> 3, cl = lane & 7;
    #pragma unroll
    for (int pass = 0; pass < 8; ++pass) {
        int qq = pass * 8 + rl;
        int t = qt * 256 + wave * 64 + qq;
        bf16x8 vrow = ld16B(&sp[qq * 72 + cl * 8]);
        __builtin_memcpy(Y + ((size_t)(b * 2048 + t)) * 1024 + h * 64 + cl * 8, &vrow, 16);
    }
}

// ---------------- launch ----------------
extern "C" void kernel_launch(void* const* d_in, const int* in_sizes, int n_in,
                              void* d_out, int out_size, void* d_ws, size_t ws_size,
                              hipStream_t stream)
{
    const float* x  = (const float*)d_in[0];
    const float* Wq = (const float*)d_in[1];
    const float* bq = (const float*)d_in[2];
    const float* Wk = (const float*)d_in[3];
    const float* bk = (const float*)d_in[4];
    const float* Wv = (const float*)d_in[5];
    const float* bv = (const float*)d_in[6];
    const float* Wo = (const float*)d_in[7];
    const float* bo = (const float*)d_in[8];
    float* out = (float*)d_out;

    const size_t NTOK = (size_t)8192 * 1024;
    const size_t WN   = (size_t)1024 * 1024;
    u16* xb  = (u16*)d_ws;
    u16* wqb = xb + NTOK;     // wq, wk, wv contiguous => [3072,1024] fused weight
    u16* wkb = wqb + WN;
    u16* wvb = wkb + WN;
    u16* wob = wvb + WN;
    u16* q   = wob + WN;
    u16* k   = q + NTOK;
    u16* vt  = k + NTOK;
    u16* y   = vt + NTOK;

    convert_kernel<<<dim3(12288), 256, 0, stream>>>(x, Wq, Wk, Wv, Wo, xb, wqb, wkb, wvb, wob);
    qkv_kernel<<<dim3(24, 64), 256, 0, stream>>>(xb, wqb, bq, bk, bv, q, k, vt);
    attn_kernel<<<dim3(64, 8), 256, 0, stream>>>(q, k, vt, y);
    proj_kernel<<<dim3(8, 64), 256, 0, stream>>>(y, wob, bo, out);
}